// Round 8
// baseline (138.621 us; speedup 1.0000x reference)
//
#include <hip/hip_runtime.h>

#define B_   4
#define NQ_  512
#define NK_  512
#define D_   512
#define H_   128

typedef __attribute__((ext_vector_type(8))) short short8;
typedef __attribute__((ext_vector_type(8))) unsigned short ushort8;
typedef __attribute__((ext_vector_type(4))) float f32x4;

__device__ __forceinline__ float fexp2(float x) { return __builtin_amdgcn_exp2f(x); }
__device__ __forceinline__ float frcp(float x)  { return __builtin_amdgcn_rcpf(x); }
__device__ __forceinline__ unsigned short f2bf(float f) {
    unsigned int u = __builtin_bit_cast(unsigned int, f);
    u += 0x7FFFu + ((u >> 16) & 1u);          // RNE
    return (unsigned short)(u >> 16);
}
__device__ __forceinline__ float bf2f(unsigned short h) {
    return __builtin_bit_cast(float, (unsigned int)h << 16);
}

// NOTE (R6): hipLaunchCooperativeKernel silently fails under graph capture.
// NOTE (R9): block-local W@V with zero-padded MFMA A-rows + global B-frags is
//            an unverified-broken construction — do not reuse.
// NOTE (R13): vl-skips in score/av: bit-identical (weights EXACT 0 at k>=vl).
// NOTE (R15): 4->3 launches: -5.5us. Launch boundaries ~3-5us each.
// NOTE (R16): av-fusion regressed but exposed score as THE bottleneck
//            (~40-44us; Occ 27%, VALU 28%, HBM 4% -> latency-bound on
//            LDS-cap occupancy + 4x barrier-serialized staging rounds).
// NOTE (R17): async-stage via pr[8] regressed score to 59-63us: WRITE_SIZE
//            76MB (vs 2MB Wbf) = SCRATCH SPILL of the conditionally-guarded
//            prefetch array (rule #20). Never reg-prefetch under runtime-
//            conditional guards. Batch-interleave itself is sound.
// NOTE (R18/this): score de-LDS'd: each lane reads its own contiguous K-row
//            (512B) straight from L1/L2 (K slab = 256KB/batch, L2-resident;
//            4 same-half waves share rows via L1). Kills the 67.6KB Ks
//            buffer (2 blocks/CU cap) and ALL staging barriers -> 4
//            blocks/CU + dynamic refill. Same read/compute order ->
//            bit-identical. projvt/av_gemm: R15/R17-verified, unchanged.

// ws layout (float offsets)
#define WS_EQK   0          // [4096][128] fp32: exp2(2*proj), Q rows 0..2047, K rows 2048..4095
#define WS_WP    524288     // [64] float4 pair table (wn0, wn1, wn0+wn1, 0)
#define WS_WBF   524544     // ushort region: [4][512][512] bf16 softmax weights
#define WS_VT    1048832    // ushort region: [4][512][512] bf16 V^T (d-major)

// ---------------------------------------------------------------------------
// projvt: grid (384), 512 thr.  (R15 verbatim — verified)
//   blocks 0..63:    Q proj (32 rows each)   -> Eqk rows 0..2047
//   blocks 64..127:  K proj (32 rows each)   -> Eqk rows 2048..4095 (vl-skip)
//   blocks 128..383: V transpose -> bf16 V^T (vl-skipped)
//   block 0 also emits the wp pair table.
// ---------------------------------------------------------------------------
__global__ __launch_bounds__(512, 4) void projvt_kernel(
    const float* __restrict__ Q, const float* __restrict__ K,
    const float* __restrict__ Wq, const float* __restrict__ Wk,
    const float* __restrict__ V, const float* __restrict__ wv,
    const int* __restrict__ valid_lens,
    float* __restrict__ wp, unsigned short* __restrict__ Vt,
    float* __restrict__ Eqk)
{
    __shared__ __align__(16) unsigned short smem_u[2 * 32 * 520];   // 66.6 KB
    const int t  = threadIdx.x;
    const int bx = blockIdx.x;

    if (bx >= 128) {
        // ----- transposeV: V (k-major fp32) -> Vt (d-major bf16) -----
        const int id = bx - 128;                  // 0..255
        const int kt = id & 7, dt = (id >> 3) & 7, b = id >> 6;
        const int vl = valid_lens[b];

        if (kt * 64 >= ((vl + 127) & ~127)) return;   // never read by av

        if (kt * 64 >= vl) {
            // dead tile inside a live 128-chunk: weights are EXACT 0 there,
            // but 0 x NaN-poison = NaN -> write finite zeros, no V read.
            #pragma unroll
            for (int p = 0; p < 2; ++p) {
                const int idx = p * 512 + t;
                const int d  = idx >> 4;
                const int k4 = (idx & 15) * 4;
                ushort4 z; z.x = 0; z.y = 0; z.z = 0; z.w = 0;
                *reinterpret_cast<ushort4*>(
                    Vt + ((size_t)b * D_ + dt * 64 + d) * NK_ + kt * 64 + k4) = z;
            }
            return;
        }

        float (*Vl)[69] = (float(*)[69])smem_u;   // 17.7 KB reuse

        #pragma unroll
        for (int p = 0; p < 2; ++p) {
            const int idx = p * 512 + t;          // 0..1023
            const int r  = idx >> 4;              // 0..63
            const int c4 = (idx & 15) * 4;
            const float4 v = *reinterpret_cast<const float4*>(
                V + ((size_t)b * NK_ + kt * 64 + r) * D_ + dt * 64 + c4);
            Vl[r][c4 + 0] = v.x; Vl[r][c4 + 1] = v.y;
            Vl[r][c4 + 2] = v.z; Vl[r][c4 + 3] = v.w;
        }
        __syncthreads();

        #pragma unroll
        for (int p = 0; p < 2; ++p) {
            const int idx = p * 512 + t;
            const int d  = idx >> 4;
            const int k4 = (idx & 15) * 4;
            ushort4 o;
            o.x = f2bf(Vl[k4 + 0][d]); o.y = f2bf(Vl[k4 + 1][d]);
            o.z = f2bf(Vl[k4 + 2][d]); o.w = f2bf(Vl[k4 + 3][d]);
            *reinterpret_cast<ushort4*>(
                Vt + ((size_t)b * D_ + dt * 64 + d) * NK_ + kt * 64 + k4) = o;
        }
        return;
    }

    // ----- proj -----
    if (bx == 0 && t < 64) {
        const float2 w2 = reinterpret_cast<const float2*>(wv)[t];
        const float wn0 = -2.0f * w2.x;
        const float wn1 = -2.0f * w2.y;
        reinterpret_cast<float4*>(wp)[t] =
            make_float4(wn0, wn1, wn0 + wn1, 0.0f);
    }

    const bool isQ = bx < 64;
    const int xr0  = isQ ? bx * 32 : (bx - 64) * 32;   // row in X
    if (!isQ) {
        const int kr = xr0 & 511;
        const int bb = xr0 >> 9;
        if (kr >= valid_lens[bb]) return;   // rows feed masked lanes only (R14)
    }
    const float* __restrict__ X  = isQ ? Q : K;
    const float* __restrict__ Wm = isQ ? Wq : Wk;
    const int er0 = isQ ? xr0 : 2048 + xr0;            // row in Eqk

    unsigned short (*Ahi)[520] = (unsigned short(*)[520])smem_u;
    unsigned short (*Alo)[520] = (unsigned short(*)[520])(smem_u + 32 * 520);

    // stage + split A (32 rows x 512 k), one pass, coalesced
    #pragma unroll
    for (int p = 0; p < 8; ++p) {
        const int idx = p * 512 + t;          // 0..4095
        const int row = idx >> 7;             // 0..31
        const int kq  = (idx & 127) * 4;      // 0..508
        const float4 v = *reinterpret_cast<const float4*>(
            X + (size_t)(xr0 + row) * D_ + kq);
        ushort4 h, l;
        h.x = f2bf(v.x); l.x = f2bf(v.x - bf2f(h.x));
        h.y = f2bf(v.y); l.y = f2bf(v.y - bf2f(h.y));
        h.z = f2bf(v.z); l.z = f2bf(v.z - bf2f(h.z));
        h.w = f2bf(v.w); l.w = f2bf(v.w - bf2f(h.w));
        *reinterpret_cast<ushort4*>(&Ahi[row][kq]) = h;
        *reinterpret_cast<ushort4*>(&Alo[row][kq]) = l;
    }
    __syncthreads();

    const int wave = __builtin_amdgcn_readfirstlane(t >> 6);  // 0..7 = col-frag
    const int lane = t & 63;
    const int m    = lane & 15;
    const int quad = lane >> 4;
    const int col  = wave * 16 + m;
    const float* __restrict__ Wcol = Wm + col;   // W[k][col], stride H_

    f32x4 a0A = {0.f,0.f,0.f,0.f}, a0B = {0.f,0.f,0.f,0.f};
    f32x4 a1A = {0.f,0.f,0.f,0.f}, a1B = {0.f,0.f,0.f,0.f};

    #pragma unroll 2
    for (int ksg = 0; ksg < 16; ++ksg) {      // 16 k-slices of 32
        const int k0 = ksg * 32 + quad * 8;
        float wr[8];
        #pragma unroll
        for (int j = 0; j < 8; ++j)
            wr[j] = Wcol[(size_t)(k0 + j) * H_];
        short8 bh, bl;
        #pragma unroll
        for (int j = 0; j < 8; ++j) {
            const unsigned short h = f2bf(wr[j]);
            bh[j] = (short)h;
            bl[j] = (short)f2bf(wr[j] - bf2f(h));
        }
        const short8 ah0 = *reinterpret_cast<const short8*>(&Ahi[     m][k0]);
        const short8 al0 = *reinterpret_cast<const short8*>(&Alo[     m][k0]);
        const short8 ah1 = *reinterpret_cast<const short8*>(&Ahi[16 + m][k0]);
        const short8 al1 = *reinterpret_cast<const short8*>(&Alo[16 + m][k0]);
        f32x4& A0 = (ksg & 1) ? a0B : a0A;    // static select (unrolled)
        f32x4& A1 = (ksg & 1) ? a1B : a1A;
        A0 = __builtin_amdgcn_mfma_f32_16x16x32_bf16(ah0, bh, A0, 0, 0, 0);
        A0 = __builtin_amdgcn_mfma_f32_16x16x32_bf16(al0, bh, A0, 0, 0, 0);
        A0 = __builtin_amdgcn_mfma_f32_16x16x32_bf16(ah0, bl, A0, 0, 0, 0);
        A1 = __builtin_amdgcn_mfma_f32_16x16x32_bf16(ah1, bh, A1, 0, 0, 0);
        A1 = __builtin_amdgcn_mfma_f32_16x16x32_bf16(al1, bh, A1, 0, 0, 0);
        A1 = __builtin_amdgcn_mfma_f32_16x16x32_bf16(ah1, bl, A1, 0, 0, 0);
    }

    const float C2 = 2.88539008177792681472f; // 2*log2(e)
    #pragma unroll
    for (int i = 0; i < 4; ++i) {
        Eqk[(size_t)(er0 + quad * 4 + i) * H_ + col] =
            fexp2(C2 * (a0A[i] + a0B[i]));
        Eqk[(size_t)(er0 + 16 + quad * 4 + i) * H_ + col] =
            fexp2(C2 * (a1A[i] + a1B[i]));
    }
}

// ---------------------------------------------------------------------------
// score_softmax: block = 4 q-rows x all 512 k, 512 thr (8 waves), grid 512.
// Wave w -> row (w>>1), k-half (w&1)*256; lane owns one k-row per chunk.
// R18: NO K LDS staging — each lane streams its own contiguous 512B K-row
// from L1/L2 (per-batch K slab = 256KB, L2-resident; 4 same-half waves
// share rows via L1). No staging barriers; tiny LDS -> 4 blocks/CU.
// R17 batch-interleave kept (b = rb&3). Same compute order -> bit-identical.
// ---------------------------------------------------------------------------
__global__ __launch_bounds__(512, 4) void score_softmax_kernel(
    const float* __restrict__ Eqk, const float* __restrict__ wp,
    const int* __restrict__ valid_lens, unsigned short* __restrict__ Wbf)
{
    const int rb   = blockIdx.x;            // 0..511
    const int t    = threadIdx.x;
    const int w    = __builtin_amdgcn_readfirstlane(t >> 6);   // 0..7
    const int lane = t & 63;
    const int rloc = w >> 1;                // 0..3
    const int half = w & 1;                 // k-half
    const int b    = rb & 3;                // R17: batch interleave
    const int row  = b * 512 + (rb >> 2) * 4 + rloc;   // q-row 0..2047

    __shared__ float redM[4][2], redS[4][2];

    const int vl = valid_lens[b];           // block-uniform

    const float4* __restrict__ Q4 =
        reinterpret_cast<const float4*>(Eqk + (size_t)row * H_);
    const float4* __restrict__ wp4 = reinterpret_cast<const float4*>(wp);
    const float4* __restrict__ Kp4 =
        reinterpret_cast<const float4*>(Eqk + (size_t)(2048 + b * NK_) * H_);

    float vals[4];

    #pragma unroll
    for (int c = 0; c < 4; ++c) {
        float s = 0.0f;
        if (half * 256 + c * 64 < vl) {     // wave-uniform skip (R13)
            const float4* __restrict__ Krow =
                Kp4 + (size_t)(half * 256 + c * 64 + lane) * 32;
            #pragma unroll 4
            for (int g = 0; g < 32; ++g) {
                const float4 kv = Krow[g];
                const float4 qa = Q4[g];
                const float4 wa = wp4[2 * g];
                const float4 wb = wp4[2 * g + 1];
                const float e0 = qa.x * kv.x;
                const float e1 = qa.y * kv.y;
                const float e2 = qa.z * kv.z;
                const float e3 = qa.w * kv.w;
                const float D01 = 1.0f + fmaf(e0, e1, e0 + e1);
                const float D23 = 1.0f + fmaf(e2, e3, e2 + e3);
                const float n01 = fmaf(wa.y, e0, fmaf(wa.x, e1, wa.z));
                const float n23 = fmaf(wb.y, e2, fmaf(wb.x, e3, wb.z));
                const float N   = fmaf(n23, D01, n01 * D23);
                s = fmaf(N, frcp(D01 * D23), s);
            }
        }
        vals[c] = s;   // dead chunks: 0, masked to -1e30 below
    }

    // per-wave masked stats over this wave's 256 k
    const float L2E = 1.44269504088896340736f;
    float m = -1e30f;
    #pragma unroll
    for (int c = 0; c < 4; ++c) {
        const int k = half * 256 + c * 64 + lane;
        vals[c] = (k < vl) ? vals[c] : -1e30f;
        m = fmaxf(m, vals[c]);
    }
    #pragma unroll
    for (int off = 32; off >= 1; off >>= 1)
        m = fmaxf(m, __shfl_xor(m, off, 64));
    float sum = 0.0f;
    #pragma unroll
    for (int c = 0; c < 4; ++c)
        sum += fexp2((vals[c] - m) * L2E);
    #pragma unroll
    for (int off = 32; off >= 1; off >>= 1)
        sum += __shfl_xor(sum, off, 64);

    if (lane == 0) { redM[rloc][half] = m; redS[rloc][half] = sum; }
    __syncthreads();

    const float m0 = redM[rloc][0], m1 = redM[rloc][1];
    const float s0 = redS[rloc][0], s1 = redS[rloc][1];
    const float M  = fmaxf(m0, m1);   // finite: vl>=1 so half 0 has a valid k
    const float S  = fmaf(s0, fexp2((m0 - M) * L2E),
                          s1 * fexp2((m1 - M) * L2E));
    const float inv = frcp(S);

    unsigned short* __restrict__ dst = Wbf + (size_t)row * NK_ + half * 256;
    #pragma unroll
    for (int c = 0; c < 4; ++c)
        dst[c * 64 + lane] = f2bf(fexp2((vals[c] - M) * L2E) * inv);
}

// ---------------------------------------------------------------------------
// av_gemm (bf16 MFMA 16x16x32): O[b] = W@V. Block 64q x 64d, 4 waves,
// grid (32,8): bx -> (batch = bx&3 interleaved, d-tile = bx>>2); by -> q-tile.
// R13: k-chunks with kc*128 >= valid_len contribute exact zeros -> break.
// ---------------------------------------------------------------------------
__global__ __launch_bounds__(256) void av_gemm_kernel(
    const unsigned short* __restrict__ Wbf, const unsigned short* __restrict__ Vt,
    const int* __restrict__ valid_lens, float* __restrict__ O)
{
    const int bx = blockIdx.x;          // 0..31
    const int b  = bx & 3;              // R17: batch interleave
    const int c0 = (bx >> 2) * 64;      // d-tile
    const int r0 = blockIdx.y * 64;     // q-tile
    const int t  = threadIdx.x;
    const int wave = __builtin_amdgcn_readfirstlane(t >> 6);
    const int lane = t & 63;
    const int m    = lane & 15;
    const int quad = lane >> 4;

    const int vl = valid_lens[b];   // block-uniform

    __shared__ unsigned short Al [64][136];
    __shared__ unsigned short Btl[64][136];

    f32x4 acc0 = {0.f,0.f,0.f,0.f}, acc1 = {0.f,0.f,0.f,0.f};
    f32x4 acc2 = {0.f,0.f,0.f,0.f}, acc3 = {0.f,0.f,0.f,0.f};

    for (int kc = 0; kc < 4; ++kc) {
        if (kc * 128 >= vl) break;    // uniform: remaining W chunks are 0
        if (kc) __syncthreads();
        #pragma unroll
        for (int p = 0; p < 4; ++p) {
            const int idx = p * 256 + t;
            const int rl = idx >> 4;
            const int k8 = (idx & 15) * 8;
            *reinterpret_cast<uint4*>(&Al[rl][k8]) =
                *reinterpret_cast<const uint4*>(
                    Wbf + ((size_t)b * NQ_ + r0 + rl) * NK_ + kc * 128 + k8);
            *reinterpret_cast<uint4*>(&Btl[rl][k8]) =
                *reinterpret_cast<const uint4*>(
                    Vt + ((size_t)b * D_ + c0 + rl) * NK_ + kc * 128 + k8);
        }
        __syncthreads();

        #pragma unroll
        for (int sub = 0; sub < 4; ++sub) {
            const int kcol = sub * 32 + quad * 8;
            const short8 a = *reinterpret_cast<const short8*>(&Al[wave * 16 + m][kcol]);
            const short8 b0 = *reinterpret_cast<const short8*>(&Btl[ 0 + m][kcol]);
            const short8 b1 = *reinterpret_cast<const short8*>(&Btl[16 + m][kcol]);
            const short8 b2 = *reinterpret_cast<const short8*>(&Btl[32 + m][kcol]);
            const short8 b3 = *reinterpret_cast<const short8*>(&Btl[48 + m][kcol]);
            acc0 = __builtin_amdgcn_mfma_f32_16x16x32_bf16(a, b0, acc0, 0, 0, 0);
            acc1 = __builtin_amdgcn_mfma_f32_16x16x32_bf16(a, b1, acc1, 0, 0, 0);
            acc2 = __builtin_amdgcn_mfma_f32_16x16x32_bf16(a, b2, acc2, 0, 0, 0);
            acc3 = __builtin_amdgcn_mfma_f32_16x16x32_bf16(a, b3, acc3, 0, 0, 0);
        }
    }

    const size_t rowbase = (size_t)b * NQ_ + r0 + wave * 16 + quad * 4;
    #pragma unroll
    for (int i = 0; i < 4; ++i) {
        float* __restrict__ orow = O + (rowbase + i) * D_ + c0 + m;
        orow[ 0] = acc0[i];
        orow[16] = acc1[i];
        orow[32] = acc2[i];
        orow[48] = acc3[i];
    }
}

extern "C" void kernel_launch(void* const* d_in, const int* in_sizes, int n_in,
                              void* d_out, int out_size, void* d_ws, size_t ws_size,
                              hipStream_t stream) {
    (void)in_sizes; (void)n_in; (void)out_size; (void)ws_size;

    const float* Q   = (const float*)d_in[0];
    const float* K   = (const float*)d_in[1];
    const float* V   = (const float*)d_in[2];
    const float* Wq  = (const float*)d_in[3];
    const float* Wk  = (const float*)d_in[4];
    const float* wv  = (const float*)d_in[5];
    const int*   vl  = (const int*)d_in[6];
    float* out = (float*)d_out;

    float* ws  = (float*)d_ws;
    float* Eqk = ws + WS_EQK;
    float* wp  = ws + WS_WP;
    unsigned short* Wbf = (unsigned short*)(ws + WS_WBF);
    unsigned short* Vt  = (unsigned short*)(ws + WS_VT);

    projvt_kernel<<<dim3(384), 512, 0, stream>>>(Q, K, Wq, Wk, V, wv, vl,
                                                 wp, Vt, Eqk);
    score_softmax_kernel<<<dim3(512), 512, 0, stream>>>(Eqk, wp, vl, Wbf);
    av_gemm_kernel<<<dim3(32, 8), 256, 0, stream>>>(Wbf, Vt, vl, out);
}

// Round 10
// 109.471 us; speedup vs baseline: 1.2663x; 1.2663x over previous
//
#include <hip/hip_runtime.h>

#define B_   4
#define NQ_  512
#define NK_  512
#define D_   512
#define H_   128

typedef __attribute__((ext_vector_type(8))) short short8;
typedef __attribute__((ext_vector_type(8))) unsigned short ushort8;
typedef __attribute__((ext_vector_type(4))) float f32x4;

__device__ __forceinline__ float fexp2(float x) { return __builtin_amdgcn_exp2f(x); }
__device__ __forceinline__ float frcp(float x)  { return __builtin_amdgcn_rcpf(x); }
__device__ __forceinline__ unsigned short f2bf(float f) {
    unsigned int u = __builtin_bit_cast(unsigned int, f);
    u += 0x7FFFu + ((u >> 16) & 1u);          // RNE
    return (unsigned short)(u >> 16);
}
__device__ __forceinline__ float bf2f(unsigned short h) {
    return __builtin_bit_cast(float, (unsigned int)h << 16);
}

// NOTE (R6): hipLaunchCooperativeKernel silently fails under graph capture.
// NOTE (R9): block-local W@V with zero-padded MFMA A-rows + global B-frags is
//            an unverified-broken construction — do not reuse.
// NOTE (R13): vl-skips in score/av: bit-identical (weights EXACT 0 at k>=vl).
// NOTE (R15): 4->3 launches: -5.5us. Launch boundaries ~3-5us each.
// NOTE (R16): av-fusion regressed but exposed score as THE bottleneck (~44us,
//            latency-bound: Occ 27%, VALU 28%, HBM 4%).
// NOTE (R17): reg-prefetch under runtime-conditional guards = scratch spill
//            (WRITE_SIZE 76MB). Rule #20. Batch-interleave itself is sound.
// NOTE (R18): de-LDS with per-lane-PRIVATE K-rows = 57us: each wave load
//            touches 64 distinct lines (row stride 512B); L1 ~1 line/cyc ->
//            ~50us of line-service. NEVER give each lane its own row.
// NOTE (R19): transpose K-proj output to EkT[b][h][k] (free in the MFMA
//            epilogue: lane's 4 acc rows = 4 consecutive k = one float4).
//            Score maps k=base+lane, loops h: loads are 64-consecutive-float
//            coalesced (4 lines/instr, 16x better), zero LDS, zero barriers,
//            8 waves/SIMD. Same values, same op order -> bit-identical.
// NOTE (R20): R19 bench was GPUAcquisitionTimeout — resubmitting unchanged.

// ws layout (float offsets)
#define WS_EQK   0          // [2048][128] fp32: exp2(2*Qproj) row-major (Q only)
#define WS_WP    524288     // [64] float4 pair table (wn0, wn1, wn0+wn1, 0)
#define WS_WBF   524544     // ushort region: [4][512][512] bf16 softmax weights
#define WS_VT    1048832    // ushort region: [4][512][512] bf16 V^T (d-major)
#define WS_EKT   1573120    // [4][128][512] fp32: exp2(2*Kproj) TRANSPOSED (h-major)

// ---------------------------------------------------------------------------
// projvt: grid (384), 512 thr.
//   blocks 0..63:    Q proj (32 rows each) -> Eqk rows 0..2047 (row-major)
//   blocks 64..127:  K proj (32 rows each) -> EkT[b][h][k] (vl-skip)
//   blocks 128..383: V transpose -> bf16 V^T (vl-skipped)
//   block 0 also emits the wp pair table.
// ---------------------------------------------------------------------------
__global__ __launch_bounds__(512, 4) void projvt_kernel(
    const float* __restrict__ Q, const float* __restrict__ K,
    const float* __restrict__ Wq, const float* __restrict__ Wk,
    const float* __restrict__ V, const float* __restrict__ wv,
    const int* __restrict__ valid_lens,
    float* __restrict__ wp, unsigned short* __restrict__ Vt,
    float* __restrict__ Eqk, float* __restrict__ EkT)
{
    __shared__ __align__(16) unsigned short smem_u[2 * 32 * 520];   // 66.6 KB
    const int t  = threadIdx.x;
    const int bx = blockIdx.x;

    if (bx >= 128) {
        // ----- transposeV: V (k-major fp32) -> Vt (d-major bf16) -----
        const int id = bx - 128;                  // 0..255
        const int kt = id & 7, dt = (id >> 3) & 7, b = id >> 6;
        const int vl = valid_lens[b];

        if (kt * 64 >= ((vl + 127) & ~127)) return;   // never read by av

        if (kt * 64 >= vl) {
            // dead tile inside a live 128-chunk: weights are EXACT 0 there,
            // but 0 x NaN-poison = NaN -> write finite zeros, no V read.
            #pragma unroll
            for (int p = 0; p < 2; ++p) {
                const int idx = p * 512 + t;
                const int d  = idx >> 4;
                const int k4 = (idx & 15) * 4;
                ushort4 z; z.x = 0; z.y = 0; z.z = 0; z.w = 0;
                *reinterpret_cast<ushort4*>(
                    Vt + ((size_t)b * D_ + dt * 64 + d) * NK_ + kt * 64 + k4) = z;
            }
            return;
        }

        float (*Vl)[69] = (float(*)[69])smem_u;   // 17.7 KB reuse

        #pragma unroll
        for (int p = 0; p < 2; ++p) {
            const int idx = p * 512 + t;          // 0..1023
            const int r  = idx >> 4;              // 0..63
            const int c4 = (idx & 15) * 4;
            const float4 v = *reinterpret_cast<const float4*>(
                V + ((size_t)b * NK_ + kt * 64 + r) * D_ + dt * 64 + c4);
            Vl[r][c4 + 0] = v.x; Vl[r][c4 + 1] = v.y;
            Vl[r][c4 + 2] = v.z; Vl[r][c4 + 3] = v.w;
        }
        __syncthreads();

        #pragma unroll
        for (int p = 0; p < 2; ++p) {
            const int idx = p * 512 + t;
            const int d  = idx >> 4;
            const int k4 = (idx & 15) * 4;
            ushort4 o;
            o.x = f2bf(Vl[k4 + 0][d]); o.y = f2bf(Vl[k4 + 1][d]);
            o.z = f2bf(Vl[k4 + 2][d]); o.w = f2bf(Vl[k4 + 3][d]);
            *reinterpret_cast<ushort4*>(
                Vt + ((size_t)b * D_ + dt * 64 + d) * NK_ + kt * 64 + k4) = o;
        }
        return;
    }

    // ----- proj -----
    if (bx == 0 && t < 64) {
        const float2 w2 = reinterpret_cast<const float2*>(wv)[t];
        const float wn0 = -2.0f * w2.x;
        const float wn1 = -2.0f * w2.y;
        reinterpret_cast<float4*>(wp)[t] =
            make_float4(wn0, wn1, wn0 + wn1, 0.0f);
    }

    const bool isQ = bx < 64;
    const int xr0  = isQ ? bx * 32 : (bx - 64) * 32;   // row in X
    if (!isQ) {
        const int kr = xr0 & 511;
        const int bb = xr0 >> 9;
        if (kr >= valid_lens[bb]) return;   // rows feed masked lanes only (R14)
    }
    const float* __restrict__ X  = isQ ? Q : K;
    const float* __restrict__ Wm = isQ ? Wq : Wk;

    unsigned short (*Ahi)[520] = (unsigned short(*)[520])smem_u;
    unsigned short (*Alo)[520] = (unsigned short(*)[520])(smem_u + 32 * 520);

    // stage + split A (32 rows x 512 k), one pass, coalesced
    #pragma unroll
    for (int p = 0; p < 8; ++p) {
        const int idx = p * 512 + t;          // 0..4095
        const int row = idx >> 7;             // 0..31
        const int kq  = (idx & 127) * 4;      // 0..508
        const float4 v = *reinterpret_cast<const float4*>(
            X + (size_t)(xr0 + row) * D_ + kq);
        ushort4 h, l;
        h.x = f2bf(v.x); l.x = f2bf(v.x - bf2f(h.x));
        h.y = f2bf(v.y); l.y = f2bf(v.y - bf2f(h.y));
        h.z = f2bf(v.z); l.z = f2bf(v.z - bf2f(h.z));
        h.w = f2bf(v.w); l.w = f2bf(v.w - bf2f(h.w));
        *reinterpret_cast<ushort4*>(&Ahi[row][kq]) = h;
        *reinterpret_cast<ushort4*>(&Alo[row][kq]) = l;
    }
    __syncthreads();

    const int wave = __builtin_amdgcn_readfirstlane(t >> 6);  // 0..7 = col-frag
    const int lane = t & 63;
    const int m    = lane & 15;
    const int quad = lane >> 4;
    const int col  = wave * 16 + m;
    const float* __restrict__ Wcol = Wm + col;   // W[k][col], stride H_

    f32x4 a0A = {0.f,0.f,0.f,0.f}, a0B = {0.f,0.f,0.f,0.f};
    f32x4 a1A = {0.f,0.f,0.f,0.f}, a1B = {0.f,0.f,0.f,0.f};

    #pragma unroll 2
    for (int ksg = 0; ksg < 16; ++ksg) {      // 16 k-slices of 32
        const int k0 = ksg * 32 + quad * 8;
        float wr[8];
        #pragma unroll
        for (int j = 0; j < 8; ++j)
            wr[j] = Wcol[(size_t)(k0 + j) * H_];
        short8 bh, bl;
        #pragma unroll
        for (int j = 0; j < 8; ++j) {
            const unsigned short h = f2bf(wr[j]);
            bh[j] = (short)h;
            bl[j] = (short)f2bf(wr[j] - bf2f(h));
        }
        const short8 ah0 = *reinterpret_cast<const short8*>(&Ahi[     m][k0]);
        const short8 al0 = *reinterpret_cast<const short8*>(&Alo[     m][k0]);
        const short8 ah1 = *reinterpret_cast<const short8*>(&Ahi[16 + m][k0]);
        const short8 al1 = *reinterpret_cast<const short8*>(&Alo[16 + m][k0]);
        f32x4& A0 = (ksg & 1) ? a0B : a0A;    // static select (unrolled)
        f32x4& A1 = (ksg & 1) ? a1B : a1A;
        A0 = __builtin_amdgcn_mfma_f32_16x16x32_bf16(ah0, bh, A0, 0, 0, 0);
        A0 = __builtin_amdgcn_mfma_f32_16x16x32_bf16(al0, bh, A0, 0, 0, 0);
        A0 = __builtin_amdgcn_mfma_f32_16x16x32_bf16(ah0, bl, A0, 0, 0, 0);
        A1 = __builtin_amdgcn_mfma_f32_16x16x32_bf16(ah1, bh, A1, 0, 0, 0);
        A1 = __builtin_amdgcn_mfma_f32_16x16x32_bf16(al1, bh, A1, 0, 0, 0);
        A1 = __builtin_amdgcn_mfma_f32_16x16x32_bf16(ah1, bl, A1, 0, 0, 0);
    }

    const float C2 = 2.88539008177792681472f; // 2*log2(e)
    if (isQ) {
        #pragma unroll
        for (int i = 0; i < 4; ++i) {
            Eqk[(size_t)(xr0 + quad * 4 + i) * H_ + col] =
                fexp2(C2 * (a0A[i] + a0B[i]));
            Eqk[(size_t)(xr0 + 16 + quad * 4 + i) * H_ + col] =
                fexp2(C2 * (a1A[i] + a1B[i]));
        }
    } else {
        // R19: transposed write EkT[b][h][k]; lane's 4 acc rows = 4
        // consecutive k -> one float4 store per m-tile.
        const int bb = xr0 >> 9;
        const int kr = xr0 & 511;
        float* __restrict__ dst =
            EkT + ((size_t)(bb * H_ + col)) * NK_ + kr;
        float4 o0, o1;
        o0.x = fexp2(C2 * (a0A[0] + a0B[0]));
        o0.y = fexp2(C2 * (a0A[1] + a0B[1]));
        o0.z = fexp2(C2 * (a0A[2] + a0B[2]));
        o0.w = fexp2(C2 * (a0A[3] + a0B[3]));
        o1.x = fexp2(C2 * (a1A[0] + a1B[0]));
        o1.y = fexp2(C2 * (a1A[1] + a1B[1]));
        o1.z = fexp2(C2 * (a1A[2] + a1B[2]));
        o1.w = fexp2(C2 * (a1A[3] + a1B[3]));
        *reinterpret_cast<float4*>(dst + quad * 4)      = o0;
        *reinterpret_cast<float4*>(dst + 16 + quad * 4) = o1;
    }
}

// ---------------------------------------------------------------------------
// score_softmax: block = 4 q-rows x all 512 k, 512 thr (8 waves), grid 512.
// Wave w -> row (w>>1), k-half (w&1)*256; lane owns k = base + lane.
// R19: reads EkT[b][h][k] — 64 consecutive floats per wave-load (coalesced,
// 4 lines/instr vs 64 for per-lane rows, R18 lesson). No LDS, no staging
// barriers, 8 waves/SIMD. Values/op-order identical -> bit-identical.
// R17 batch-interleave kept (b = rb&3).
// ---------------------------------------------------------------------------
__global__ __launch_bounds__(512, 4) void score_softmax_kernel(
    const float* __restrict__ Eqk, const float* __restrict__ EkT,
    const float* __restrict__ wp,
    const int* __restrict__ valid_lens, unsigned short* __restrict__ Wbf)
{
    const int rb   = blockIdx.x;            // 0..511
    const int t    = threadIdx.x;
    const int w    = __builtin_amdgcn_readfirstlane(t >> 6);   // 0..7
    const int lane = t & 63;
    const int rloc = w >> 1;                // 0..3
    const int half = w & 1;                 // k-half
    const int b    = rb & 3;                // R17: batch interleave
    const int row  = b * 512 + (rb >> 2) * 4 + rloc;   // q-row 0..2047

    __shared__ float redM[4][2], redS[4][2];

    const int vl = valid_lens[b];           // block-uniform

    const float4* __restrict__ Q4 =
        reinterpret_cast<const float4*>(Eqk + (size_t)row * H_);
    const float4* __restrict__ wp4 = reinterpret_cast<const float4*>(wp);
    const float* __restrict__ EkTb = EkT + (size_t)b * (H_ * NK_);

    float vals[4];

    #pragma unroll
    for (int c = 0; c < 4; ++c) {
        float s = 0.0f;
        if (half * 256 + c * 64 < vl) {     // wave-uniform skip (R13)
            const float* __restrict__ Ek =
                EkTb + half * 256 + c * 64 + lane;   // stride NK_ per h
            #pragma unroll 4
            for (int g = 0; g < 32; ++g) {
                const float k0v = Ek[(size_t)(4 * g + 0) * NK_];
                const float k1v = Ek[(size_t)(4 * g + 1) * NK_];
                const float k2v = Ek[(size_t)(4 * g + 2) * NK_];
                const float k3v = Ek[(size_t)(4 * g + 3) * NK_];
                const float4 qa = Q4[g];
                const float4 wa = wp4[2 * g];
                const float4 wb = wp4[2 * g + 1];
                const float e0 = qa.x * k0v;
                const float e1 = qa.y * k1v;
                const float e2 = qa.z * k2v;
                const float e3 = qa.w * k3v;
                const float D01 = 1.0f + fmaf(e0, e1, e0 + e1);
                const float D23 = 1.0f + fmaf(e2, e3, e2 + e3);
                const float n01 = fmaf(wa.y, e0, fmaf(wa.x, e1, wa.z));
                const float n23 = fmaf(wb.y, e2, fmaf(wb.x, e3, wb.z));
                const float N   = fmaf(n23, D01, n01 * D23);
                s = fmaf(N, frcp(D01 * D23), s);
            }
        }
        vals[c] = s;   // dead chunks: 0, masked to -1e30 below
    }

    // per-wave masked stats over this wave's 256 k
    const float L2E = 1.44269504088896340736f;
    float m = -1e30f;
    #pragma unroll
    for (int c = 0; c < 4; ++c) {
        const int k = half * 256 + c * 64 + lane;
        vals[c] = (k < vl) ? vals[c] : -1e30f;
        m = fmaxf(m, vals[c]);
    }
    #pragma unroll
    for (int off = 32; off >= 1; off >>= 1)
        m = fmaxf(m, __shfl_xor(m, off, 64));
    float sum = 0.0f;
    #pragma unroll
    for (int c = 0; c < 4; ++c)
        sum += fexp2((vals[c] - m) * L2E);
    #pragma unroll
    for (int off = 32; off >= 1; off >>= 1)
        sum += __shfl_xor(sum, off, 64);

    if (lane == 0) { redM[rloc][half] = m; redS[rloc][half] = sum; }
    __syncthreads();

    const float m0 = redM[rloc][0], m1 = redM[rloc][1];
    const float s0 = redS[rloc][0], s1 = redS[rloc][1];
    const float M  = fmaxf(m0, m1);   // finite: vl>=1 so half 0 has a valid k
    const float S  = fmaf(s0, fexp2((m0 - M) * L2E),
                          s1 * fexp2((m1 - M) * L2E));
    const float inv = frcp(S);

    unsigned short* __restrict__ dst = Wbf + (size_t)row * NK_ + half * 256;
    #pragma unroll
    for (int c = 0; c < 4; ++c)
        dst[c * 64 + lane] = f2bf(fexp2((vals[c] - M) * L2E) * inv);
}

// ---------------------------------------------------------------------------
// av_gemm (bf16 MFMA 16x16x32): O[b] = W@V. Block 64q x 64d, 4 waves,
// grid (32,8): bx -> (batch = bx&3 interleaved, d-tile = bx>>2); by -> q-tile.
// R13: k-chunks with kc*128 >= valid_len contribute exact zeros -> break.
// ---------------------------------------------------------------------------
__global__ __launch_bounds__(256) void av_gemm_kernel(
    const unsigned short* __restrict__ Wbf, const unsigned short* __restrict__ Vt,
    const int* __restrict__ valid_lens, float* __restrict__ O)
{
    const int bx = blockIdx.x;          // 0..31
    const int b  = bx & 3;              // R17: batch interleave
    const int c0 = (bx >> 2) * 64;      // d-tile
    const int r0 = blockIdx.y * 64;     // q-tile
    const int t  = threadIdx.x;
    const int wave = __builtin_amdgcn_readfirstlane(t >> 6);
    const int lane = t & 63;
    const int m    = lane & 15;
    const int quad = lane >> 4;

    const int vl = valid_lens[b];   // block-uniform

    __shared__ unsigned short Al [64][136];
    __shared__ unsigned short Btl[64][136];

    f32x4 acc0 = {0.f,0.f,0.f,0.f}, acc1 = {0.f,0.f,0.f,0.f};
    f32x4 acc2 = {0.f,0.f,0.f,0.f}, acc3 = {0.f,0.f,0.f,0.f};

    for (int kc = 0; kc < 4; ++kc) {
        if (kc * 128 >= vl) break;    // uniform: remaining W chunks are 0
        if (kc) __syncthreads();
        #pragma unroll
        for (int p = 0; p < 4; ++p) {
            const int idx = p * 256 + t;
            const int rl = idx >> 4;
            const int k8 = (idx & 15) * 8;
            *reinterpret_cast<uint4*>(&Al[rl][k8]) =
                *reinterpret_cast<const uint4*>(
                    Wbf + ((size_t)b * NQ_ + r0 + rl) * NK_ + kc * 128 + k8);
            *reinterpret_cast<uint4*>(&Btl[rl][k8]) =
                *reinterpret_cast<const uint4*>(
                    Vt + ((size_t)b * D_ + c0 + rl) * NK_ + kc * 128 + k8);
        }
        __syncthreads();

        #pragma unroll
        for (int sub = 0; sub < 4; ++sub) {
            const int kcol = sub * 32 + quad * 8;
            const short8 a = *reinterpret_cast<const short8*>(&Al[wave * 16 + m][kcol]);
            const short8 b0 = *reinterpret_cast<const short8*>(&Btl[ 0 + m][kcol]);
            const short8 b1 = *reinterpret_cast<const short8*>(&Btl[16 + m][kcol]);
            const short8 b2 = *reinterpret_cast<const short8*>(&Btl[32 + m][kcol]);
            const short8 b3 = *reinterpret_cast<const short8*>(&Btl[48 + m][kcol]);
            acc0 = __builtin_amdgcn_mfma_f32_16x16x32_bf16(a, b0, acc0, 0, 0, 0);
            acc1 = __builtin_amdgcn_mfma_f32_16x16x32_bf16(a, b1, acc1, 0, 0, 0);
            acc2 = __builtin_amdgcn_mfma_f32_16x16x32_bf16(a, b2, acc2, 0, 0, 0);
            acc3 = __builtin_amdgcn_mfma_f32_16x16x32_bf16(a, b3, acc3, 0, 0, 0);
        }
    }

    const size_t rowbase = (size_t)b * NQ_ + r0 + wave * 16 + quad * 4;
    #pragma unroll
    for (int i = 0; i < 4; ++i) {
        float* __restrict__ orow = O + (rowbase + i) * D_ + c0 + m;
        orow[ 0] = acc0[i];
        orow[16] = acc1[i];
        orow[32] = acc2[i];
        orow[48] = acc3[i];
    }
}

extern "C" void kernel_launch(void* const* d_in, const int* in_sizes, int n_in,
                              void* d_out, int out_size, void* d_ws, size_t ws_size,
                              hipStream_t stream) {
    (void)in_sizes; (void)n_in; (void)out_size; (void)ws_size;

    const float* Q   = (const float*)d_in[0];
    const float* K   = (const float*)d_in[1];
    const float* V   = (const float*)d_in[2];
    const float* Wq  = (const float*)d_in[3];
    const float* Wk  = (const float*)d_in[4];
    const float* wv  = (const float*)d_in[5];
    const int*   vl  = (const int*)d_in[6];
    float* out = (float*)d_out;

    float* ws  = (float*)d_ws;
    float* Eqk = ws + WS_EQK;
    float* wp  = ws + WS_WP;
    float* EkT = ws + WS_EKT;
    unsigned short* Wbf = (unsigned short*)(ws + WS_WBF);
    unsigned short* Vt  = (unsigned short*)(ws + WS_VT);

    projvt_kernel<<<dim3(384), 512, 0, stream>>>(Q, K, Wq, Wk, V, wv, vl,
                                                 wp, Vt, Eqk, EkT);
    score_softmax_kernel<<<dim3(512), 512, 0, stream>>>(Eqk, EkT, wp, vl, Wbf);
    av_gemm_kernel<<<dim3(32, 8), 256, 0, stream>>>(Wbf, Vt, vl, out);
}